// Round 2
// baseline (169.712 us; speedup 1.0000x reference)
//
#include <hip/hip_runtime.h>

// DispCorrLayer: out[b,d,h,w] = (1/C) * sum_c in1[b,c,h,w] * in2[b,c,h,w-(D-d)]
// (zero when w + d < D). B=4 C=32 H=256 W=512 D=128, fp32.
//
// R2 structure: block = (b, h, 256-w chunk). 4 waves; each wave covers all
// 256 w (lane l -> w0 = 4l, dense 16B-stride LDS reads = canonical
// conflict-free pattern) and a 32-d stripe (acc[32][4] in VGPRs).
// All 32 channels staged once (80 KB LDS -> exactly 2 blocks/CU), single
// __syncthreads, then a sync-free FMA loop.

#define BB 4
#define CC 32
#define HH 256
#define WW 512
#define DD 128

#define WCHUNK 256
#define TILE2 (WCHUNK + DD)   // 384
#define DT 32                 // d per wave
#define NTHREADS 256          // 4 waves

__global__ __launch_bounds__(NTHREADS, 2)
void disp_corr_kernel(const float* __restrict__ in1,
                      const float* __restrict__ in2,
                      float* __restrict__ out) {
    __shared__ float s1[CC][WCHUNK];   // 32 KB
    __shared__ float s2[CC][TILE2];    // 48 KB

    const int tid = threadIdx.x;
    const int blk = blockIdx.x;              // 0..2047
    const int wc  = blk & 1;
    const int h   = (blk >> 1) & (HH - 1);
    const int b   = blk >> 9;
    const int wbase = wc * WCHUNK;

    const size_t planebase = ((size_t)b * CC) * HH * WW + (size_t)h * WW;
    const size_t cstride   = (size_t)HH * WW;

    // ---- stage s1: CC*WCHUNK/4 = 2048 quads, 8 per thread, coalesced ----
    #pragma unroll
    for (int i = tid; i < CC * WCHUNK / 4; i += NTHREADS) {
        const int c = i >> 6;                // 64 quads per row
        const int q = i & 63;
        *(float4*)&s1[c][q * 4] =
            *(const float4*)(in1 + planebase + (size_t)c * cstride + wbase + q * 4);
    }
    // ---- stage s2 halo tile: CC*TILE2/4 = 3072 quads, 12 per thread ----
    #pragma unroll
    for (int i = tid; i < CC * TILE2 / 4; i += NTHREADS) {
        const int c = i / (TILE2 / 4);       // 96 quads per row
        const int q = i % (TILE2 / 4);
        const int wp = wbase + q * 4 - DD;   // global w' (multiple of 4)
        float4 v = make_float4(0.f, 0.f, 0.f, 0.f);
        if (wp >= 0)
            v = *(const float4*)(in2 + planebase + (size_t)c * cstride + wp);
        *(float4*)&s2[c][q * 4] = v;
    }
    __syncthreads();

    // ---- compute: wave wv owns d in [32wv, 32wv+32); lane l owns w0 = 4l ----
    const int lane = tid & 63;
    const int wv   = tid >> 6;
    const int w0   = lane * 4;
    const int d0   = wv * DT;
    const int t0   = w0 + d0;                // s2 index of (wi=0, di=0)

    float acc[DT][4] = {};

    #pragma unroll 2
    for (int c = 0; c < CC; ++c) {
        float a[4];
        *(float4*)a = *(const float4*)&s1[c][w0];
        float win[DT + 4];                   // 36 floats = 9 quads
        #pragma unroll
        for (int j = 0; j < (DT + 4) / 4; ++j)
            *(float4*)&win[j * 4] = *(const float4*)&s2[c][t0 + j * 4];
        #pragma unroll
        for (int di = 0; di < DT; ++di)
            #pragma unroll
            for (int wi = 0; wi < 4; ++wi)
                acc[di][wi] += a[wi] * win[di + wi];
    }

    // ---- write out: per di, lanes store 16B at 16B stride = 1KB coalesced ----
    const float scale = 1.0f / (float)CC;
    #pragma unroll
    for (int di = 0; di < DT; ++di) {
        const int d = d0 + di;
        float4 v = make_float4(acc[di][0] * scale, acc[di][1] * scale,
                               acc[di][2] * scale, acc[di][3] * scale);
        *(float4*)(out + (((size_t)b * DD + d) * HH + h) * WW + wbase + w0) = v;
    }
}

extern "C" void kernel_launch(void* const* d_in, const int* in_sizes, int n_in,
                              void* d_out, int out_size, void* d_ws, size_t ws_size,
                              hipStream_t stream) {
    const float* in1 = (const float*)d_in[0];
    const float* in2 = (const float*)d_in[1];
    float* out = (float*)d_out;
    const int nblocks = BB * HH * (WW / WCHUNK);   // 2048
    disp_corr_kernel<<<nblocks, NTHREADS, 0, stream>>>(in1, in2, out);
}

// Round 3
// 139.318 us; speedup vs baseline: 1.2182x; 1.2182x over previous
//
#include <hip/hip_runtime.h>

// DispCorrLayer: out[b,d,h,w] = (1/C) * sum_c in1[b,c,h,w] * in2[b,c,h,w-(D-d)]
// (zero when w + d < D). B=4 C=32 H=256 W=512 D=128, fp32.
//
// R3: block = (b, h, d-half of 64). Full W=512 row per block. LDS holds bf16
// copies of in1 row-tile [32][512] and in2 halo tile [32][576] (68 KB ->
// 2 blocks/CU, 16 waves/CU). 8 waves: wave wv owns d in [d0+8wv, +8),
// lane owns w0 = 8*lane. Per c per wave: 3 ds_read_b128 -> 64 FMAs.

#define BB 4
#define CC 32
#define HH 256
#define WW 512
#define DD 128

#define DHALF 64
#define S2W (WW + DHALF)     // 576
#define NT 512               // 8 waves
#define DT 8                 // d per wave
#define WT 8                 // w per lane

__device__ __forceinline__ float bflo(unsigned int u) {
    union { unsigned int i; float f; } v; v.i = u << 16; return v.f;
}
__device__ __forceinline__ float bfhi(unsigned int u) {
    union { unsigned int i; float f; } v; v.i = u & 0xffff0000u; return v.f;
}
__device__ __forceinline__ unsigned int pack2(float a, float b) {
    // RNE bf16 round of a (low half) and b (high half)
    union { float f; unsigned int i; } x, y; x.f = a; y.f = b;
    unsigned int xi = x.i + 0x7fffu + ((x.i >> 16) & 1u);
    unsigned int yi = y.i + 0x7fffu + ((y.i >> 16) & 1u);
    return (xi >> 16) | (yi & 0xffff0000u);
}

__global__ __launch_bounds__(NT, 4)
void disp_corr_kernel(const float* __restrict__ in1,
                      const float* __restrict__ in2,
                      float* __restrict__ out) {
    __shared__ unsigned int s1[CC][WW / 2];    // bf16x2, 32 KB
    __shared__ unsigned int s2[CC][S2W / 2];   // bf16x2, 36 KB

    const int tid = threadIdx.x;

    // XCD-aware swizzle: keep the two d-halves of one (b,h) on the same XCD.
    const int nblk = BB * HH * 2;                       // 2048
    const int sw = (blockIdx.x & 7) * (nblk / 8) + (blockIdx.x >> 3);
    const int ds = sw & 1;
    const int h  = (sw >> 1) & (HH - 1);
    const int b  = sw >> 9;
    const int d0 = ds * DHALF;

    const size_t base0 = (size_t)b * CC * HH * WW + (size_t)h * WW;
    const size_t cstr  = (size_t)HH * WW;

    // ---- stage in1 row as bf16: 2048 8-float chunks, 4 per thread ----
    #pragma unroll
    for (int k = 0; k < 4; ++k) {
        const int i = tid + k * NT;
        const int c = i >> 6;                 // 64 chunks per row
        const int o = (i & 63) * 8;
        const float4* p = (const float4*)(in1 + base0 + c * cstr + o);
        const float4 u = p[0], v = p[1];
        unsigned int* dst = &s1[c][o >> 1];
        dst[0] = pack2(u.x, u.y); dst[1] = pack2(u.z, u.w);
        dst[2] = pack2(v.x, v.y); dst[3] = pack2(v.z, v.w);
    }
    // ---- stage in2 halo tile as bf16: s2[c][t] = in2[w' = t + d0 - 128] ----
    for (int i = tid; i < CC * (S2W / 8); i += NT) {    // 2304 chunks
        const int c = i / (S2W / 8);
        const int q = i - c * (S2W / 8);
        const int t = q * 8;
        const int wp = t + d0 - DD;           // multiple of 8 -> no straddle
        float4 u = make_float4(0.f, 0.f, 0.f, 0.f);
        float4 v = make_float4(0.f, 0.f, 0.f, 0.f);
        if (wp >= 0) {                        // wp+7 <= 511 always
            const float4* p = (const float4*)(in2 + base0 + c * cstr + wp);
            u = p[0]; v = p[1];
        }
        unsigned int* dst = &s2[c][t >> 1];
        dst[0] = pack2(u.x, u.y); dst[1] = pack2(u.z, u.w);
        dst[2] = pack2(v.x, v.y); dst[3] = pack2(v.z, v.w);
    }
    __syncthreads();

    // ---- compute ----
    const int lane = tid & 63;
    const int wv   = tid >> 6;
    const int w0   = lane * WT;               // 8*lane
    const int t0   = w0 + wv * DT;            // s2 float index of (di=0, wi=0)

    float acc[DT][WT] = {};
    const unsigned int* s1r = &s1[0][w0 >> 1];
    const unsigned int* s2r = &s2[0][t0 >> 1];

    for (int c = 0; c < CC; ++c) {
        const uint4 ap = *(const uint4*)(s1r + c * (WW / 2));
        const uint4 p0 = *(const uint4*)(s2r + c * (S2W / 2));
        const uint4 p1 = *(const uint4*)(s2r + c * (S2W / 2) + 4);
        float a[WT] = { bflo(ap.x), bfhi(ap.x), bflo(ap.y), bfhi(ap.y),
                        bflo(ap.z), bfhi(ap.z), bflo(ap.w), bfhi(ap.w) };
        float wn[16] = { bflo(p0.x), bfhi(p0.x), bflo(p0.y), bfhi(p0.y),
                         bflo(p0.z), bfhi(p0.z), bflo(p0.w), bfhi(p0.w),
                         bflo(p1.x), bfhi(p1.x), bflo(p1.y), bfhi(p1.y),
                         bflo(p1.z), bfhi(p1.z), bflo(p1.w), bfhi(p1.w) };
        #pragma unroll
        for (int di = 0; di < DT; ++di)
            #pragma unroll
            for (int wi = 0; wi < WT; ++wi)
                acc[di][wi] += a[wi] * wn[di + wi];
    }

    // ---- write out: per di, 8 contiguous floats per lane, 2 KB per wave ----
    const float sc = 1.0f / (float)CC;
    #pragma unroll
    for (int di = 0; di < DT; ++di) {
        const int d = d0 + wv * DT + di;
        float* op = out + (((size_t)b * DD + d) * HH + h) * WW + w0;
        float4 o0 = make_float4(acc[di][0] * sc, acc[di][1] * sc,
                                acc[di][2] * sc, acc[di][3] * sc);
        float4 o1 = make_float4(acc[di][4] * sc, acc[di][5] * sc,
                                acc[di][6] * sc, acc[di][7] * sc);
        ((float4*)op)[0] = o0;
        ((float4*)op)[1] = o1;
    }
}

extern "C" void kernel_launch(void* const* d_in, const int* in_sizes, int n_in,
                              void* d_out, int out_size, void* d_ws, size_t ws_size,
                              hipStream_t stream) {
    const float* in1 = (const float*)d_in[0];
    const float* in2 = (const float*)d_in[1];
    float* out = (float*)d_out;
    const int nblocks = BB * HH * 2;          // 2048
    disp_corr_kernel<<<nblocks, NT, 0, stream>>>(in1, in2, out);
}